// Round 7
// baseline (453.753 us; speedup 1.0000x reference)
//
#include <hip/hip_runtime.h>

typedef __bf16 bf16;
typedef __bf16 bf16x4 __attribute__((ext_vector_type(4)));
typedef __bf16 bf16x8 __attribute__((ext_vector_type(8)));
typedef float f32x4 __attribute__((ext_vector_type(4)));

#define D_MODEL 1024
#define PROJ    256
#define SEQ     2048
#define BATCH   2
#define TOK     4096   // BATCH*SEQ
#define NH      16
#define DH      64
#define NEG_BIG (-1e30f)
#define PSTR    72     // LDS P-tile stride (elements)
#define QSCALE  0.18033688011112042f   // 0.125 * log2(e), folded into Qh

#if __has_builtin(__builtin_amdgcn_exp2f)
#define EXP2(x) __builtin_amdgcn_exp2f(x)
#else
#define EXP2(x) exp2f(x)
#endif

// ---------------------------------------------------------------------------
// DPP 16-lane row sum (groups are contiguous 16-lane DPP rows).
template <int CTRL>
__device__ __forceinline__ float dppmov(float x) {
    int i = __builtin_bit_cast(int, x);
    i = __builtin_amdgcn_update_dpp(i, i, CTRL, 0xf, 0xf, false);
    return __builtin_bit_cast(float, i);
}
__device__ __forceinline__ float rowsum16(float v) {
    v += dppmov<0xB1>(v);
    v += dppmov<0x4E>(v);
    v += dppmov<0x141>(v);
    v += dppmov<0x140>(v);
    return v;
}

// ---------------------------------------------------------------------------
// One kernel for all weight prep: W_o cvt + 4 transposes (fp32 -> bf16 n-major).
__global__ void prep_weights_kernel(
    const float* __restrict__ W_o,  const float* __restrict__ W_dq,
    const float* __restrict__ W_dkv, const float* __restrict__ W_uq,
    const float* __restrict__ W_ukv,
    bf16* __restrict__ Wo16, bf16* __restrict__ Wt_dq, bf16* __restrict__ Wt_dkv,
    bf16* __restrict__ Wt_uq, bf16* __restrict__ Wt_ukv) {
    const int R0 = 1048576;
    const int R1 = R0 + 262144;
    const int R2 = R1 + 262144;
    const int R3 = R2 + 262144;
    const int R4 = R3 + 524288;
    for (int i = blockIdx.x * blockDim.x + threadIdx.x; i < R4;
         i += gridDim.x * blockDim.x) {
        if (i < R0) {
            Wo16[i] = (bf16)W_o[i];
        } else if (i < R1) {
            int j = i - R0, n = j >> 10, k = j & 1023;
            Wt_dq[j] = (bf16)W_dq[k * 256 + n];
        } else if (i < R2) {
            int j = i - R1, n = j >> 10, k = j & 1023;
            Wt_dkv[j] = (bf16)W_dkv[k * 256 + n];
        } else if (i < R3) {
            int j = i - R2, n = j >> 8, k = j & 255;
            Wt_uq[j] = (bf16)W_uq[k * 1024 + n];
        } else {
            int j = i - R3, n = j >> 8, k = j & 255;
            Wt_ukv[j] = (bf16)W_ukv[k * 2048 + n];
        }
    }
}

// ---------------------------------------------------------------------------
// Dual LN-GEMM: blockIdx.y=0 -> cq=LN(x@W_dq), =1 -> ckv=LN(x@W_dkv).
__global__ __launch_bounds__(256) void gemm_ln_kernel(
    const float* __restrict__ x,
    const bf16* __restrict__ Wt_q, const bf16* __restrict__ Wt_kv,
    const float* __restrict__ q_g, const float* __restrict__ q_b,
    const float* __restrict__ kv_g, const float* __restrict__ kv_b,
    bf16* __restrict__ cq, bf16* __restrict__ ckv) {
    const int K = 1024;
    const bf16* Wt = blockIdx.y ? Wt_kv : Wt_q;
    const float* gamma = blockIdx.y ? kv_g : q_g;
    const float* beta  = blockIdx.y ? kv_b : q_b;
    bf16* out = blockIdx.y ? ckv : cq;

    const int m0 = blockIdx.x * 16;
    const int wv = threadIdx.x >> 6;
    const int lane = threadIdx.x & 63;
    const int g = lane >> 4;
    const int ln16 = lane & 15;
    const int ncol0 = wv * 64;

    f32x4 acc[4] = {};
    const float* arow = x + (size_t)(m0 + ln16) * K + g * 8;
    for (int k0 = 0; k0 < K; k0 += 32) {
        f32x4 f0 = *(const f32x4*)(arow + k0);
        f32x4 f1 = *(const f32x4*)(arow + k0 + 4);
        bf16x8 a;
#pragma unroll
        for (int j = 0; j < 4; ++j) { a[j] = (bf16)f0[j]; a[4 + j] = (bf16)f1[j]; }
#pragma unroll
        for (int t = 0; t < 4; ++t) {
            const bf16* bp = Wt + (size_t)(ncol0 + 16 * t + ln16) * K + k0 + g * 8;
            bf16x8 b = *(const bf16x8*)bp;
            acc[t] = __builtin_amdgcn_mfma_f32_16x16x32_bf16(a, b, acc[t], 0, 0, 0);
        }
    }

    float s1[4], s2[4];
#pragma unroll
    for (int r = 0; r < 4; ++r) {
        float a = 0.f, b = 0.f;
#pragma unroll
        for (int t = 0; t < 4; ++t) { float v = acc[t][r]; a += v; b += v * v; }
        s1[r] = rowsum16(a); s2[r] = rowsum16(b);
    }
    __shared__ float red1[4][16];
    __shared__ float red2[4][16];
    if (ln16 == 0) {
#pragma unroll
        for (int r = 0; r < 4; ++r) {
            red1[wv][g * 4 + r] = s1[r];
            red2[wv][g * 4 + r] = s2[r];
        }
    }
    __syncthreads();
#pragma unroll
    for (int r = 0; r < 4; ++r) {
        int row = g * 4 + r;
        float t1 = red1[0][row] + red1[1][row] + red1[2][row] + red1[3][row];
        float t2 = red2[0][row] + red2[1][row] + red2[2][row] + red2[3][row];
        float mu = t1 * (1.0f / 256.0f);
        float var = t2 * (1.0f / 256.0f) - mu * mu;
        float rs = rsqrtf(var + 1e-5f);
#pragma unroll
        for (int t = 0; t < 4; ++t) {
            int col = ncol0 + 16 * t + ln16;
            float v = (acc[t][r] - mu) * rs * gamma[col] + beta[col];
            out[(size_t)(m0 + row) * PROJ + col] = (bf16)v;
        }
    }
}

// ---------------------------------------------------------------------------
// Generic MFMA GEMM (round-5 config: 32-row M-tiles). A[M][K] row-major bf16,
// Bt[N][K] n-major bf16, fp32 acc.
// MODE 0: C[M][N] row-major, OutT.
// MODE 1: C = head-major bf16 [b*16+h][2048][64], values pre-scaled by QSCALE.
// MODE 2: cols<1024 -> C = Kh head-major; cols>=1024 -> C2 = Vt [bh][64][2048]
template <int MODE, typename OutT>
__global__ __launch_bounds__(256) void gemm_kernel(
    const bf16* __restrict__ A, const bf16* __restrict__ Bt,
    OutT* __restrict__ C, bf16* __restrict__ C2, int M, int N, int K) {
    const int m0 = blockIdx.x * 32;
    const int n0 = blockIdx.y * 256 + (threadIdx.x >> 6) * 64;
    const int lane = threadIdx.x & 63;
    const int g = lane >> 4;
    const int ln16 = lane & 15;

    f32x4 acc[2][4] = {};
    const bf16* a0 = A + (size_t)(m0 + ln16) * K + g * 8;
    const bf16* a1 = a0 + (size_t)16 * K;
    for (int k0 = 0; k0 < K; k0 += 32) {
        bf16x8 A0 = *(const bf16x8*)(a0 + k0);
        bf16x8 A1 = *(const bf16x8*)(a1 + k0);
#pragma unroll
        for (int t = 0; t < 4; ++t) {
            const bf16* bp = Bt + (size_t)(n0 + 16 * t + ln16) * K + k0 + g * 8;
            bf16x8 b = *(const bf16x8*)bp;
            acc[0][t] = __builtin_amdgcn_mfma_f32_16x16x32_bf16(A0, b, acc[0][t], 0, 0, 0);
            acc[1][t] = __builtin_amdgcn_mfma_f32_16x16x32_bf16(A1, b, acc[1][t], 0, 0, 0);
        }
    }
#pragma unroll
    for (int s = 0; s < 2; ++s)
#pragma unroll
        for (int t = 0; t < 4; ++t) {
            const int col = n0 + 16 * t + ln16;
            const int tok0 = m0 + 16 * s + g * 4;
            if (MODE == 2 && col >= 1024) {
                int cc = col - 1024;
                int h = cc >> 6, d = cc & 63;
                int b = tok0 >> 11, sq = tok0 & 2047;
                bf16x4 pk;
#pragma unroll
                for (int r = 0; r < 4; ++r) pk[r] = (bf16)acc[s][t][r];
                *(bf16x4*)(C2 + ((size_t)((b * 16 + h) * 64 + d) * SEQ + sq)) = pk;
            } else {
#pragma unroll
                for (int r = 0; r < 4; ++r) {
                    int row = tok0 + r;
                    float v = acc[s][t][r];
                    if (MODE == 0) {
                        C[(size_t)row * N + col] = (OutT)v;
                    } else {
                        if (MODE == 1) v *= QSCALE;
                        int h = col >> 6, d = col & 63;
                        int b = row >> 11, sq = row & 2047;
                        C[((size_t)((b * 16 + h) * 2048 + sq)) * 64 + d] = (OutT)v;
                    }
                }
            }
        }
}

// ---------------------------------------------------------------------------
// Split-K paired flash attention (fixed-max softmax => k-split is a pure sum).
// Wave = (pair pid, parity sp): pid gives (bh, p) with q-tiles qbL=p*16,
// qbH=(127-p)*16; wave sp processes k-tiles kt = sp, sp+2, ... Partial fp32
// O/l written to scratch; combine_kernel sums parities and normalizes.
__device__ __forceinline__ void load_kfrags(const bf16* __restrict__ Kbh, int k0,
                                            int g, int ln16, bf16x8* Kf) {
#pragma unroll
    for (int c = 0; c < 4; ++c) {
        const bf16* kp = Kbh + (size_t)(k0 + 16 * c + ln16) * DH + g * 8;
        Kf[2 * c]     = *(const bf16x8*)kp;
        Kf[2 * c + 1] = *(const bf16x8*)(kp + 32);
    }
}
__device__ __forceinline__ void load_vfrags(const bf16* __restrict__ Vbh, int k0,
                                            int g, int ln16, bf16x8* Vf) {
#pragma unroll
    for (int t = 0; t < 4; ++t) {
        const bf16* vp = Vbh + (size_t)(16 * t + ln16) * SEQ + k0 + g * 8;
        Vf[2 * t]     = *(const bf16x8*)vp;
        Vf[2 * t + 1] = *(const bf16x8*)(vp + 32);
    }
}

__device__ __forceinline__ void qk_exp(
    int k0, int qb, bool masked, int g, int ln16,
    bf16x8 aq0, bf16x8 aq1, const bf16x8* Kf,
    unsigned short* __restrict__ pb, float* liacc) {
    f32x4 sc[4];
#pragma unroll
    for (int c = 0; c < 4; ++c) {
        f32x4 z = {};
        z = __builtin_amdgcn_mfma_f32_16x16x32_bf16(aq0, Kf[2 * c], z, 0, 0, 0);
        z = __builtin_amdgcn_mfma_f32_16x16x32_bf16(aq1, Kf[2 * c + 1], z, 0, 0, 0);
        sc[c] = z;
    }
    if (masked) {
#pragma unroll
        for (int r = 0; r < 4; ++r) {
            int qrow = qb + g * 4 + r;
#pragma unroll
            for (int c = 0; c < 4; ++c) {
                int col = k0 + 16 * c + ln16;
                if (col > qrow) sc[c][r] = NEG_BIG;
            }
        }
    }
#pragma unroll
    for (int r = 0; r < 4; ++r) {
        float p0 = EXP2(sc[0][r]), p1 = EXP2(sc[1][r]);
        float p2 = EXP2(sc[2][r]), p3 = EXP2(sc[3][r]);
        sc[0][r] = p0; sc[1][r] = p1; sc[2][r] = p2; sc[3][r] = p3;
        liacc[r] += (p0 + p1) + (p2 + p3);
    }
#pragma unroll
    for (int c = 0; c < 4; ++c)
#pragma unroll
        for (int r = 0; r < 4; ++r) {
            bf16 pv = (bf16)sc[c][r];
            pb[(g * 4 + r) * PSTR + 16 * c + ln16] =
                __builtin_bit_cast(unsigned short, pv);
        }
}

__device__ __forceinline__ void pv_accum(
    const unsigned short* __restrict__ pb, int g, int ln16,
    const bf16x8* Vf, f32x4* o) {
    bf16x8 pf0 = *(const bf16x8*)(pb + ln16 * PSTR + g * 8);
    bf16x8 pf1 = *(const bf16x8*)(pb + ln16 * PSTR + 32 + g * 8);
#pragma unroll
    for (int t = 0; t < 4; ++t) {
        o[t] = __builtin_amdgcn_mfma_f32_16x16x32_bf16(pf0, Vf[2 * t], o[t], 0, 0, 0);
        o[t] = __builtin_amdgcn_mfma_f32_16x16x32_bf16(pf1, Vf[2 * t + 1], o[t], 0, 0, 0);
    }
}

__global__ __launch_bounds__(256, 4) void attn_kernel(
    const bf16* __restrict__ Qh, const bf16* __restrict__ Kh,
    const bf16* __restrict__ Vt,
    float* __restrict__ Opart, float* __restrict__ lpart) {
    __shared__ alignas(16) unsigned short pbuf[4][2][16 * PSTR];

    const int wv = threadIdx.x >> 6;
    const int lane = threadIdx.x & 63;
    const int g = lane >> 4;
    const int ln16 = lane & 15;

    const int wid = blockIdx.x * 4 + wv;   // 0..4095
    const int pid = wid >> 1;              // 0..2047
    const int sp  = wid & 1;               // kt parity
    const int bh = pid & 31;
    const int p  = pid >> 5;               // 0..63
    const int qbL = p * 16;
    const int qbH = (127 - p) * 16;
    const int lastL = p >> 2;
    const int lastH = (127 - p) >> 2;

    const bf16* Kbh = Kh + (size_t)bh * SEQ * DH;
    const bf16* Vbh = Vt + (size_t)bh * DH * SEQ;

    const bf16* qpL = Qh + ((size_t)bh * SEQ + qbL + ln16) * DH + g * 8;
    const bf16* qpH = Qh + ((size_t)bh * SEQ + qbH + ln16) * DH + g * 8;
    bf16x8 aqL0 = *(const bf16x8*)qpL, aqL1 = *(const bf16x8*)(qpL + 32);
    bf16x8 aqH0 = *(const bf16x8*)qpH, aqH1 = *(const bf16x8*)(qpH + 32);

    f32x4 oL[4] = {}, oH[4] = {};
    float liL[4] = {}, liH[4] = {};

    unsigned short* pbL = &pbuf[wv][0][0];
    unsigned short* pbH = &pbuf[wv][1][0];

    bf16x8 Kf[8], Kn[8], Vf[8];
    load_kfrags(Kbh, sp * 64, g, ln16, Kf);
#pragma unroll
    for (int i = 0; i < 8; ++i) Kn[i] = Kf[i];

    for (int kt = sp; kt <= lastH; kt += 2) {
        const int k0 = kt * 64;
        load_vfrags(Vbh, k0, g, ln16, Vf);
        if (kt + 2 <= lastH) load_kfrags(Kbh, k0 + 128, g, ln16, Kn);

        const bool actL = (kt <= lastL);
        if (actL) qk_exp(k0, qbL, kt == lastL, g, ln16, aqL0, aqL1, Kf, pbL, liL);
        qk_exp(k0, qbH, kt == lastH, g, ln16, aqH0, aqH1, Kf, pbH, liH);
        __asm__ volatile("s_waitcnt lgkmcnt(0)" ::: "memory");
        if (actL) pv_accum(pbL, g, ln16, Vf, oL);
        pv_accum(pbH, g, ln16, Vf, oH);

#pragma unroll
        for (int i = 0; i < 8; ++i) Kf[i] = Kn[i];
    }

    // partial epilogue: slot(pid,sp,which) = (pid*2+sp)*2 + which
    const int slotL = (pid * 2 + sp) * 2;
    const int slotH = slotL + 1;
    float* OL = Opart + (size_t)slotL * 1024;
    float* OH = Opart + (size_t)slotH * 1024;
#pragma unroll
    for (int t = 0; t < 4; ++t)
#pragma unroll
        for (int r = 0; r < 4; ++r) {
            int e = (g * 4 + r) * 64 + 16 * t + ln16;
            OL[e] = oL[t][r];
            OH[e] = oH[t][r];
        }
#pragma unroll
    for (int r = 0; r < 4; ++r) {
        float sL = rowsum16(liL[r]);
        float sH = rowsum16(liH[r]);
        if (ln16 == 0) {
            lpart[slotL * 16 + g * 4 + r] = sL;
            lpart[slotH * 16 + g * 4 + r] = sH;
        }
    }
}

// ---------------------------------------------------------------------------
// Combine: sum the two parity partials, normalize, write AT token-major.
__global__ __launch_bounds__(256) void combine_kernel(
    const float* __restrict__ Opart, const float* __restrict__ lpart,
    bf16* __restrict__ AT) {
    int idx = blockIdx.x * 256 + threadIdx.x;      // 32*2048*64 = 4.19M
    int d = idx & 63;
    int s = (idx >> 6) & 2047;
    int bh = idx >> 17;
    int qt = s >> 4, row = s & 15;
    int which = (qt >= 64) ? 1 : 0;
    int p = which ? (127 - qt) : qt;
    int pid = p * 32 + bh;
    int s0 = (pid * 2 + 0) * 2 + which;
    int s1 = (pid * 2 + 1) * 2 + which;
    float O = Opart[(size_t)s0 * 1024 + row * 64 + d] +
              Opart[(size_t)s1 * 1024 + row * 64 + d];
    float l = lpart[s0 * 16 + row] + lpart[s1 * 16 + row];
    int token = (bh >> 4) * 2048 + s;
    int col = (bh & 15) * 64 + d;
    AT[(size_t)token * 1024 + col] = (bf16)(O / l);
}

// ---------------------------------------------------------------------------
extern "C" void kernel_launch(void* const* d_in, const int* in_sizes, int n_in,
                              void* d_out, int out_size, void* d_ws, size_t ws_size,
                              hipStream_t stream) {
    const float* x     = (const float*)d_in[0];
    const float* W_dq  = (const float*)d_in[1];
    const float* W_uq  = (const float*)d_in[2];
    const float* q_g   = (const float*)d_in[3];
    const float* q_b   = (const float*)d_in[4];
    const float* W_dkv = (const float*)d_in[5];
    const float* W_ukv = (const float*)d_in[6];
    const float* kv_g  = (const float*)d_in[7];
    const float* kv_b  = (const float*)d_in[8];
    const float* W_o   = (const float*)d_in[9];

    char* ws = (char*)d_ws;
    size_t off = 0;
    bf16* Wo16   = (bf16*)(ws + off); off += (size_t)D_MODEL * D_MODEL * 2;
    bf16* Wt_dq  = (bf16*)(ws + off); off += (size_t)PROJ * D_MODEL * 2;
    bf16* Wt_dkv = (bf16*)(ws + off); off += (size_t)PROJ * D_MODEL * 2;
    bf16* Wt_uq  = (bf16*)(ws + off); off += (size_t)D_MODEL * PROJ * 2;
    bf16* Wt_ukv = (bf16*)(ws + off); off += (size_t)(2 * D_MODEL) * PROJ * 2;
    bf16* cq     = (bf16*)(ws + off); off += (size_t)TOK * PROJ * 2;
    bf16* ckv    = (bf16*)(ws + off); off += (size_t)TOK * PROJ * 2;
    bf16* Qh     = (bf16*)(ws + off); off += (size_t)TOK * D_MODEL * 2;
    bf16* Kh     = (bf16*)(ws + off); off += (size_t)TOK * D_MODEL * 2;
    bf16* Vt     = (bf16*)(ws + off); off += (size_t)TOK * D_MODEL * 2;
    bf16* AT     = (bf16*)(ws + off); off += (size_t)TOK * D_MODEL * 2;
    float* Opart = (float*)(ws + off); off += (size_t)8192 * 1024 * 4;   // 33.5 MB
    float* lpart = (float*)(ws + off); off += (size_t)8192 * 16 * 4;

    prep_weights_kernel<<<2048, 256, 0, stream>>>(
        W_o, W_dq, W_dkv, W_uq, W_ukv, Wo16, Wt_dq, Wt_dkv, Wt_uq, Wt_ukv);

    gemm_ln_kernel<<<dim3(TOK / 16, 2), 256, 0, stream>>>(
        x, Wt_dq, Wt_dkv, q_g, q_b, kv_g, kv_b, cq, ckv);

    gemm_kernel<1, bf16><<<dim3(TOK / 32, D_MODEL / 256), 256, 0, stream>>>(
        cq, Wt_uq, Qh, nullptr, TOK, D_MODEL, PROJ);
    gemm_kernel<2, bf16><<<dim3(TOK / 32, (2 * D_MODEL) / 256), 256, 0, stream>>>(
        ckv, Wt_ukv, Kh, Vt, TOK, 2 * D_MODEL, PROJ);

    attn_kernel<<<1024, 256, 0, stream>>>(Qh, Kh, Vt, Opart, lpart);
    combine_kernel<<<(32 * 2048 * 64) / 256, 256, 0, stream>>>(Opart, lpart, AT);

    gemm_kernel<0, float><<<dim3(TOK / 32, D_MODEL / 256), 256, 0, stream>>>(
        AT, Wo16, (float*)d_out, nullptr, TOK, D_MODEL, D_MODEL);
}

// Round 8
// 324.510 us; speedup vs baseline: 1.3983x; 1.3983x over previous
//
#include <hip/hip_runtime.h>

typedef __bf16 bf16;
typedef __bf16 bf16x4 __attribute__((ext_vector_type(4)));
typedef __bf16 bf16x8 __attribute__((ext_vector_type(8)));
typedef float f32x4 __attribute__((ext_vector_type(4)));

#define D_MODEL 1024
#define PROJ    256
#define SEQ     2048
#define BATCH   2
#define TOK     4096   // BATCH*SEQ
#define NH      16
#define DH      64
#define NEG_BIG (-1e30f)
#define PSTR    72     // LDS P-tile stride (elements)
#define QSCALE  0.18033688011112042f   // 0.125 * log2(e), folded into Qh

#if __has_builtin(__builtin_amdgcn_exp2f)
#define EXP2(x) __builtin_amdgcn_exp2f(x)
#else
#define EXP2(x) exp2f(x)
#endif

// ---------------------------------------------------------------------------
// DPP 16-lane row sum (groups are contiguous 16-lane DPP rows).
template <int CTRL>
__device__ __forceinline__ float dppmov(float x) {
    int i = __builtin_bit_cast(int, x);
    i = __builtin_amdgcn_update_dpp(i, i, CTRL, 0xf, 0xf, false);
    return __builtin_bit_cast(float, i);
}
__device__ __forceinline__ float rowsum16(float v) {
    v += dppmov<0xB1>(v);
    v += dppmov<0x4E>(v);
    v += dppmov<0x141>(v);
    v += dppmov<0x140>(v);
    return v;
}

// ---------------------------------------------------------------------------
// One kernel for all weight prep: W_o cvt + 4 transposes (fp32 -> bf16 n-major).
__global__ void prep_weights_kernel(
    const float* __restrict__ W_o,  const float* __restrict__ W_dq,
    const float* __restrict__ W_dkv, const float* __restrict__ W_uq,
    const float* __restrict__ W_ukv,
    bf16* __restrict__ Wo16, bf16* __restrict__ Wt_dq, bf16* __restrict__ Wt_dkv,
    bf16* __restrict__ Wt_uq, bf16* __restrict__ Wt_ukv) {
    const int R0 = 1048576;
    const int R1 = R0 + 262144;
    const int R2 = R1 + 262144;
    const int R3 = R2 + 262144;
    const int R4 = R3 + 524288;
    for (int i = blockIdx.x * blockDim.x + threadIdx.x; i < R4;
         i += gridDim.x * blockDim.x) {
        if (i < R0) {
            Wo16[i] = (bf16)W_o[i];
        } else if (i < R1) {
            int j = i - R0, n = j >> 10, k = j & 1023;
            Wt_dq[j] = (bf16)W_dq[k * 256 + n];
        } else if (i < R2) {
            int j = i - R1, n = j >> 10, k = j & 1023;
            Wt_dkv[j] = (bf16)W_dkv[k * 256 + n];
        } else if (i < R3) {
            int j = i - R2, n = j >> 8, k = j & 255;
            Wt_uq[j] = (bf16)W_uq[k * 1024 + n];
        } else {
            int j = i - R3, n = j >> 8, k = j & 255;
            Wt_ukv[j] = (bf16)W_ukv[k * 2048 + n];
        }
    }
}

// ---------------------------------------------------------------------------
// Dual LN-GEMM: blockIdx.y=0 -> cq=LN(x@W_dq), =1 -> ckv=LN(x@W_dkv).
__global__ __launch_bounds__(256) void gemm_ln_kernel(
    const float* __restrict__ x,
    const bf16* __restrict__ Wt_q, const bf16* __restrict__ Wt_kv,
    const float* __restrict__ q_g, const float* __restrict__ q_b,
    const float* __restrict__ kv_g, const float* __restrict__ kv_b,
    bf16* __restrict__ cq, bf16* __restrict__ ckv) {
    const int K = 1024;
    const bf16* Wt = blockIdx.y ? Wt_kv : Wt_q;
    const float* gamma = blockIdx.y ? kv_g : q_g;
    const float* beta  = blockIdx.y ? kv_b : q_b;
    bf16* out = blockIdx.y ? ckv : cq;

    const int m0 = blockIdx.x * 16;
    const int wv = threadIdx.x >> 6;
    const int lane = threadIdx.x & 63;
    const int g = lane >> 4;
    const int ln16 = lane & 15;
    const int ncol0 = wv * 64;

    f32x4 acc[4] = {};
    const float* arow = x + (size_t)(m0 + ln16) * K + g * 8;
    for (int k0 = 0; k0 < K; k0 += 32) {
        f32x4 f0 = *(const f32x4*)(arow + k0);
        f32x4 f1 = *(const f32x4*)(arow + k0 + 4);
        bf16x8 a;
#pragma unroll
        for (int j = 0; j < 4; ++j) { a[j] = (bf16)f0[j]; a[4 + j] = (bf16)f1[j]; }
#pragma unroll
        for (int t = 0; t < 4; ++t) {
            const bf16* bp = Wt + (size_t)(ncol0 + 16 * t + ln16) * K + k0 + g * 8;
            bf16x8 b = *(const bf16x8*)bp;
            acc[t] = __builtin_amdgcn_mfma_f32_16x16x32_bf16(a, b, acc[t], 0, 0, 0);
        }
    }

    float s1[4], s2[4];
#pragma unroll
    for (int r = 0; r < 4; ++r) {
        float a = 0.f, b = 0.f;
#pragma unroll
        for (int t = 0; t < 4; ++t) { float v = acc[t][r]; a += v; b += v * v; }
        s1[r] = rowsum16(a); s2[r] = rowsum16(b);
    }
    __shared__ float red1[4][16];
    __shared__ float red2[4][16];
    if (ln16 == 0) {
#pragma unroll
        for (int r = 0; r < 4; ++r) {
            red1[wv][g * 4 + r] = s1[r];
            red2[wv][g * 4 + r] = s2[r];
        }
    }
    __syncthreads();
#pragma unroll
    for (int r = 0; r < 4; ++r) {
        int row = g * 4 + r;
        float t1 = red1[0][row] + red1[1][row] + red1[2][row] + red1[3][row];
        float t2 = red2[0][row] + red2[1][row] + red2[2][row] + red2[3][row];
        float mu = t1 * (1.0f / 256.0f);
        float var = t2 * (1.0f / 256.0f) - mu * mu;
        float rs = rsqrtf(var + 1e-5f);
#pragma unroll
        for (int t = 0; t < 4; ++t) {
            int col = ncol0 + 16 * t + ln16;
            float v = (acc[t][r] - mu) * rs * gamma[col] + beta[col];
            out[(size_t)(m0 + row) * PROJ + col] = (bf16)v;
        }
    }
}

// ---------------------------------------------------------------------------
// Generic MFMA GEMM (32-row M-tiles). A[M][K] row-major bf16,
// Bt[N][K] n-major bf16, fp32 acc.
// MODE 0: C[M][N] row-major, OutT.
// MODE 1: C = head-major bf16 [b*16+h][2048][64], values pre-scaled by QSCALE.
// MODE 2: cols<1024 -> C = Kh head-major; cols>=1024 -> C2 = Vt [bh][64][2048]
template <int MODE, typename OutT>
__global__ __launch_bounds__(256) void gemm_kernel(
    const bf16* __restrict__ A, const bf16* __restrict__ Bt,
    OutT* __restrict__ C, bf16* __restrict__ C2, int M, int N, int K) {
    const int m0 = blockIdx.x * 32;
    const int n0 = blockIdx.y * 256 + (threadIdx.x >> 6) * 64;
    const int lane = threadIdx.x & 63;
    const int g = lane >> 4;
    const int ln16 = lane & 15;

    f32x4 acc[2][4] = {};
    const bf16* a0 = A + (size_t)(m0 + ln16) * K + g * 8;
    const bf16* a1 = a0 + (size_t)16 * K;
    for (int k0 = 0; k0 < K; k0 += 32) {
        bf16x8 A0 = *(const bf16x8*)(a0 + k0);
        bf16x8 A1 = *(const bf16x8*)(a1 + k0);
#pragma unroll
        for (int t = 0; t < 4; ++t) {
            const bf16* bp = Bt + (size_t)(n0 + 16 * t + ln16) * K + k0 + g * 8;
            bf16x8 b = *(const bf16x8*)bp;
            acc[0][t] = __builtin_amdgcn_mfma_f32_16x16x32_bf16(A0, b, acc[0][t], 0, 0, 0);
            acc[1][t] = __builtin_amdgcn_mfma_f32_16x16x32_bf16(A1, b, acc[1][t], 0, 0, 0);
        }
    }
#pragma unroll
    for (int s = 0; s < 2; ++s)
#pragma unroll
        for (int t = 0; t < 4; ++t) {
            const int col = n0 + 16 * t + ln16;
            const int tok0 = m0 + 16 * s + g * 4;
            if (MODE == 2 && col >= 1024) {
                int cc = col - 1024;
                int h = cc >> 6, d = cc & 63;
                int b = tok0 >> 11, sq = tok0 & 2047;
                bf16x4 pk;
#pragma unroll
                for (int r = 0; r < 4; ++r) pk[r] = (bf16)acc[s][t][r];
                *(bf16x4*)(C2 + ((size_t)((b * 16 + h) * 64 + d) * SEQ + sq)) = pk;
            } else {
#pragma unroll
                for (int r = 0; r < 4; ++r) {
                    int row = tok0 + r;
                    float v = acc[s][t][r];
                    if (MODE == 0) {
                        C[(size_t)row * N + col] = (OutT)v;
                    } else {
                        if (MODE == 1) v *= QSCALE;
                        int h = col >> 6, d = col & 63;
                        int b = row >> 11, sq = row & 2047;
                        C[((size_t)((b * 16 + h) * 2048 + sq)) * 64 + d] = (OutT)v;
                    }
                }
            }
        }
}

// ---------------------------------------------------------------------------
// Split-K paired flash attention (fixed-max softmax => k-split is a pure sum).
// Wave = (pair pid, parity sp): pid gives (bh, p) with q-tiles qbL=p*16,
// qbH=(127-p)*16; wave sp processes k-tiles kt = sp, sp+2, ... Partial fp32
// O/l written to scratch; combine_kernel sums parities and normalizes.
__device__ __forceinline__ void load_kfrags(const bf16* __restrict__ Kbh, int k0,
                                            int g, int ln16, bf16x8* Kf) {
#pragma unroll
    for (int c = 0; c < 4; ++c) {
        const bf16* kp = Kbh + (size_t)(k0 + 16 * c + ln16) * DH + g * 8;
        Kf[2 * c]     = *(const bf16x8*)kp;
        Kf[2 * c + 1] = *(const bf16x8*)(kp + 32);
    }
}
__device__ __forceinline__ void load_vfrags(const bf16* __restrict__ Vbh, int k0,
                                            int g, int ln16, bf16x8* Vf) {
#pragma unroll
    for (int t = 0; t < 4; ++t) {
        const bf16* vp = Vbh + (size_t)(16 * t + ln16) * SEQ + k0 + g * 8;
        Vf[2 * t]     = *(const bf16x8*)vp;
        Vf[2 * t + 1] = *(const bf16x8*)(vp + 32);
    }
}

__device__ __forceinline__ void qk_exp(
    int k0, int qb, bool masked, int g, int ln16,
    bf16x8 aq0, bf16x8 aq1, const bf16x8* Kf,
    unsigned short* __restrict__ pb, float* liacc) {
    f32x4 sc[4];
#pragma unroll
    for (int c = 0; c < 4; ++c) {
        f32x4 z = {};
        z = __builtin_amdgcn_mfma_f32_16x16x32_bf16(aq0, Kf[2 * c], z, 0, 0, 0);
        z = __builtin_amdgcn_mfma_f32_16x16x32_bf16(aq1, Kf[2 * c + 1], z, 0, 0, 0);
        sc[c] = z;
    }
    if (masked) {
#pragma unroll
        for (int r = 0; r < 4; ++r) {
            int qrow = qb + g * 4 + r;
#pragma unroll
            for (int c = 0; c < 4; ++c) {
                int col = k0 + 16 * c + ln16;
                if (col > qrow) sc[c][r] = NEG_BIG;
            }
        }
    }
#pragma unroll
    for (int r = 0; r < 4; ++r) {
        float p0 = EXP2(sc[0][r]), p1 = EXP2(sc[1][r]);
        float p2 = EXP2(sc[2][r]), p3 = EXP2(sc[3][r]);
        sc[0][r] = p0; sc[1][r] = p1; sc[2][r] = p2; sc[3][r] = p3;
        liacc[r] += (p0 + p1) + (p2 + p3);
    }
#pragma unroll
    for (int c = 0; c < 4; ++c)
#pragma unroll
        for (int r = 0; r < 4; ++r) {
            bf16 pv = (bf16)sc[c][r];
            pb[(g * 4 + r) * PSTR + 16 * c + ln16] =
                __builtin_bit_cast(unsigned short, pv);
        }
}

__device__ __forceinline__ void pv_accum(
    const unsigned short* __restrict__ pb, int g, int ln16,
    const bf16x8* Vf, f32x4* o) {
    bf16x8 pf0 = *(const bf16x8*)(pb + ln16 * PSTR + g * 8);
    bf16x8 pf1 = *(const bf16x8*)(pb + ln16 * PSTR + 32 + g * 8);
#pragma unroll
    for (int t = 0; t < 4; ++t) {
        o[t] = __builtin_amdgcn_mfma_f32_16x16x32_bf16(pf0, Vf[2 * t], o[t], 0, 0, 0);
        o[t] = __builtin_amdgcn_mfma_f32_16x16x32_bf16(pf1, Vf[2 * t + 1], o[t], 0, 0, 0);
    }
}

// NOTE: __launch_bounds__(256,2) — NOT (256,4). Round 7's (256,4) clamped the
// allocator to 64 VGPRs and spilled every fragment to scratch (345MB FETCH /
// 686MB WRITE on the attn dispatch). At ~104 VGPRs the HW naturally fits
// 4 waves/SIMD anyway (floor(512/104)=4).
__global__ __launch_bounds__(256, 2) void attn_kernel(
    const bf16* __restrict__ Qh, const bf16* __restrict__ Kh,
    const bf16* __restrict__ Vt,
    float* __restrict__ Opart, float* __restrict__ lpart) {
    __shared__ alignas(16) unsigned short pbuf[4][2][16 * PSTR];

    const int wv = threadIdx.x >> 6;
    const int lane = threadIdx.x & 63;
    const int g = lane >> 4;
    const int ln16 = lane & 15;

    const int wid = blockIdx.x * 4 + wv;   // 0..4095
    const int pid = wid >> 1;              // 0..2047
    const int sp  = wid & 1;               // kt parity
    const int bh = pid & 31;
    const int p  = pid >> 5;               // 0..63
    const int qbL = p * 16;
    const int qbH = (127 - p) * 16;
    const int lastL = p >> 2;
    const int lastH = (127 - p) >> 2;

    const bf16* Kbh = Kh + (size_t)bh * SEQ * DH;
    const bf16* Vbh = Vt + (size_t)bh * DH * SEQ;

    const bf16* qpL = Qh + ((size_t)bh * SEQ + qbL + ln16) * DH + g * 8;
    const bf16* qpH = Qh + ((size_t)bh * SEQ + qbH + ln16) * DH + g * 8;
    bf16x8 aqL0 = *(const bf16x8*)qpL, aqL1 = *(const bf16x8*)(qpL + 32);
    bf16x8 aqH0 = *(const bf16x8*)qpH, aqH1 = *(const bf16x8*)(qpH + 32);

    f32x4 oL[4] = {}, oH[4] = {};
    float liL[4] = {}, liH[4] = {};

    unsigned short* pbL = &pbuf[wv][0][0];
    unsigned short* pbH = &pbuf[wv][1][0];

    bf16x8 Kf[8], Kn[8], Vf[8];
    load_kfrags(Kbh, sp * 64, g, ln16, Kf);
#pragma unroll
    for (int i = 0; i < 8; ++i) Kn[i] = Kf[i];

    for (int kt = sp; kt <= lastH; kt += 2) {
        const int k0 = kt * 64;
        load_vfrags(Vbh, k0, g, ln16, Vf);
        if (kt + 2 <= lastH) load_kfrags(Kbh, k0 + 128, g, ln16, Kn);

        const bool actL = (kt <= lastL);
        if (actL) qk_exp(k0, qbL, kt == lastL, g, ln16, aqL0, aqL1, Kf, pbL, liL);
        qk_exp(k0, qbH, kt == lastH, g, ln16, aqH0, aqH1, Kf, pbH, liH);
        __asm__ volatile("s_waitcnt lgkmcnt(0)" ::: "memory");
        if (actL) pv_accum(pbL, g, ln16, Vf, oL);
        pv_accum(pbH, g, ln16, Vf, oH);

#pragma unroll
        for (int i = 0; i < 8; ++i) Kf[i] = Kn[i];
    }

    // partial epilogue: slot(pid,sp,which) = (pid*2+sp)*2 + which
    const int slotL = (pid * 2 + sp) * 2;
    const int slotH = slotL + 1;
    float* OL = Opart + (size_t)slotL * 1024;
    float* OH = Opart + (size_t)slotH * 1024;
#pragma unroll
    for (int t = 0; t < 4; ++t)
#pragma unroll
        for (int r = 0; r < 4; ++r) {
            int e = (g * 4 + r) * 64 + 16 * t + ln16;
            OL[e] = oL[t][r];
            OH[e] = oH[t][r];
        }
#pragma unroll
    for (int r = 0; r < 4; ++r) {
        float sL = rowsum16(liL[r]);
        float sH = rowsum16(liH[r]);
        if (ln16 == 0) {
            lpart[slotL * 16 + g * 4 + r] = sL;
            lpart[slotH * 16 + g * 4 + r] = sH;
        }
    }
}

// ---------------------------------------------------------------------------
// Combine: sum the two parity partials, normalize, write AT token-major.
__global__ __launch_bounds__(256) void combine_kernel(
    const float* __restrict__ Opart, const float* __restrict__ lpart,
    bf16* __restrict__ AT) {
    int idx = blockIdx.x * 256 + threadIdx.x;      // 32*2048*64 = 4.19M
    int d = idx & 63;
    int s = (idx >> 6) & 2047;
    int bh = idx >> 17;
    int qt = s >> 4, row = s & 15;
    int which = (qt >= 64) ? 1 : 0;
    int p = which ? (127 - qt) : qt;
    int pid = p * 32 + bh;
    int s0 = (pid * 2 + 0) * 2 + which;
    int s1 = (pid * 2 + 1) * 2 + which;
    float O = Opart[(size_t)s0 * 1024 + row * 64 + d] +
              Opart[(size_t)s1 * 1024 + row * 64 + d];
    float l = lpart[s0 * 16 + row] + lpart[s1 * 16 + row];
    int token = (bh >> 4) * 2048 + s;
    int col = (bh & 15) * 64 + d;
    AT[(size_t)token * 1024 + col] = (bf16)(O / l);
}

// ---------------------------------------------------------------------------
extern "C" void kernel_launch(void* const* d_in, const int* in_sizes, int n_in,
                              void* d_out, int out_size, void* d_ws, size_t ws_size,
                              hipStream_t stream) {
    const float* x     = (const float*)d_in[0];
    const float* W_dq  = (const float*)d_in[1];
    const float* W_uq  = (const float*)d_in[2];
    const float* q_g   = (const float*)d_in[3];
    const float* q_b   = (const float*)d_in[4];
    const float* W_dkv = (const float*)d_in[5];
    const float* W_ukv = (const float*)d_in[6];
    const float* kv_g  = (const float*)d_in[7];
    const float* kv_b  = (const float*)d_in[8];
    const float* W_o   = (const float*)d_in[9];

    char* ws = (char*)d_ws;
    size_t off = 0;
    bf16* Wo16   = (bf16*)(ws + off); off += (size_t)D_MODEL * D_MODEL * 2;
    bf16* Wt_dq  = (bf16*)(ws + off); off += (size_t)PROJ * D_MODEL * 2;
    bf16* Wt_dkv = (bf16*)(ws + off); off += (size_t)PROJ * D_MODEL * 2;
    bf16* Wt_uq  = (bf16*)(ws + off); off += (size_t)D_MODEL * PROJ * 2;
    bf16* Wt_ukv = (bf16*)(ws + off); off += (size_t)(2 * D_MODEL) * PROJ * 2;
    bf16* cq     = (bf16*)(ws + off); off += (size_t)TOK * PROJ * 2;
    bf16* ckv    = (bf16*)(ws + off); off += (size_t)TOK * PROJ * 2;
    bf16* Qh     = (bf16*)(ws + off); off += (size_t)TOK * D_MODEL * 2;
    bf16* Kh     = (bf16*)(ws + off); off += (size_t)TOK * D_MODEL * 2;
    bf16* Vt     = (bf16*)(ws + off); off += (size_t)TOK * D_MODEL * 2;
    bf16* AT     = (bf16*)(ws + off); off += (size_t)TOK * D_MODEL * 2;
    float* Opart = (float*)(ws + off); off += (size_t)8192 * 1024 * 4;   // 33.5 MB
    float* lpart = (float*)(ws + off); off += (size_t)8192 * 16 * 4;

    prep_weights_kernel<<<2048, 256, 0, stream>>>(
        W_o, W_dq, W_dkv, W_uq, W_ukv, Wo16, Wt_dq, Wt_dkv, Wt_uq, Wt_ukv);

    gemm_ln_kernel<<<dim3(TOK / 16, 2), 256, 0, stream>>>(
        x, Wt_dq, Wt_dkv, q_g, q_b, kv_g, kv_b, cq, ckv);

    gemm_kernel<1, bf16><<<dim3(TOK / 32, D_MODEL / 256), 256, 0, stream>>>(
        cq, Wt_uq, Qh, nullptr, TOK, D_MODEL, PROJ);
    gemm_kernel<2, bf16><<<dim3(TOK / 32, (2 * D_MODEL) / 256), 256, 0, stream>>>(
        ckv, Wt_ukv, Kh, Vt, TOK, 2 * D_MODEL, PROJ);

    attn_kernel<<<1024, 256, 0, stream>>>(Qh, Kh, Vt, Opart, lpart);
    combine_kernel<<<(32 * 2048 * 64) / 256, 256, 0, stream>>>(Opart, lpart, AT);

    gemm_kernel<0, float><<<dim3(TOK / 32, D_MODEL / 256), 256, 0, stream>>>(
        AT, Wo16, (float*)d_out, nullptr, TOK, D_MODEL, D_MODEL);
}

// Round 9
// 278.630 us; speedup vs baseline: 1.6285x; 1.1647x over previous
//
#include <hip/hip_runtime.h>

typedef __bf16 bf16;
typedef __bf16 bf16x4 __attribute__((ext_vector_type(4)));
typedef __bf16 bf16x8 __attribute__((ext_vector_type(8)));
typedef float f32x4 __attribute__((ext_vector_type(4)));

#define D_MODEL 1024
#define PROJ    256
#define SEQ     2048
#define BATCH   2
#define TOK     4096   // BATCH*SEQ
#define NH      16
#define DH      64
#define NEG_BIG (-1e30f)
#define PSTR    72     // LDS P-tile stride (elements)
#define QSCALE  0.18033688011112042f   // 0.125 * log2(e), folded into Qh

#if __has_builtin(__builtin_amdgcn_exp2f)
#define EXP2(x) __builtin_amdgcn_exp2f(x)
#else
#define EXP2(x) exp2f(x)
#endif

typedef __attribute__((address_space(3))) unsigned int  lds_u32;
typedef __attribute__((address_space(1))) unsigned int  glb_u32;

// async 16B/lane global->LDS (gfx950 global_load_lds_dwordx4).
// LDS dest is wave-uniform base + lane*16; gsrc is per-lane.
__device__ __forceinline__ void gl2lds16(const void* gsrc, void* ldst) {
    __builtin_amdgcn_global_load_lds((const glb_u32*)gsrc, (lds_u32*)ldst, 16, 0, 0);
}

// ---------------------------------------------------------------------------
// DPP 16-lane row sum (groups are contiguous 16-lane DPP rows).
template <int CTRL>
__device__ __forceinline__ float dppmov(float x) {
    int i = __builtin_bit_cast(int, x);
    i = __builtin_amdgcn_update_dpp(i, i, CTRL, 0xf, 0xf, false);
    return __builtin_bit_cast(float, i);
}
__device__ __forceinline__ float rowsum16(float v) {
    v += dppmov<0xB1>(v);
    v += dppmov<0x4E>(v);
    v += dppmov<0x141>(v);
    v += dppmov<0x140>(v);
    return v;
}

// ---------------------------------------------------------------------------
// One kernel for all weight prep: W_o cvt + 4 transposes (fp32 -> bf16 n-major).
__global__ void prep_weights_kernel(
    const float* __restrict__ W_o,  const float* __restrict__ W_dq,
    const float* __restrict__ W_dkv, const float* __restrict__ W_uq,
    const float* __restrict__ W_ukv,
    bf16* __restrict__ Wo16, bf16* __restrict__ Wt_dq, bf16* __restrict__ Wt_dkv,
    bf16* __restrict__ Wt_uq, bf16* __restrict__ Wt_ukv) {
    const int R0 = 1048576;
    const int R1 = R0 + 262144;
    const int R2 = R1 + 262144;
    const int R3 = R2 + 262144;
    const int R4 = R3 + 524288;
    for (int i = blockIdx.x * blockDim.x + threadIdx.x; i < R4;
         i += gridDim.x * blockDim.x) {
        if (i < R0) {
            Wo16[i] = (bf16)W_o[i];
        } else if (i < R1) {
            int j = i - R0, n = j >> 10, k = j & 1023;
            Wt_dq[j] = (bf16)W_dq[k * 256 + n];
        } else if (i < R2) {
            int j = i - R1, n = j >> 10, k = j & 1023;
            Wt_dkv[j] = (bf16)W_dkv[k * 256 + n];
        } else if (i < R3) {
            int j = i - R2, n = j >> 8, k = j & 255;
            Wt_uq[j] = (bf16)W_uq[k * 1024 + n];
        } else {
            int j = i - R3, n = j >> 8, k = j & 255;
            Wt_ukv[j] = (bf16)W_ukv[k * 2048 + n];
        }
    }
}

// ---------------------------------------------------------------------------
// Dual LN-GEMM: blockIdx.y=0 -> cq=LN(x@W_dq), =1 -> ckv=LN(x@W_dkv).
__global__ __launch_bounds__(256) void gemm_ln_kernel(
    const float* __restrict__ x,
    const bf16* __restrict__ Wt_q, const bf16* __restrict__ Wt_kv,
    const float* __restrict__ q_g, const float* __restrict__ q_b,
    const float* __restrict__ kv_g, const float* __restrict__ kv_b,
    bf16* __restrict__ cq, bf16* __restrict__ ckv) {
    const int K = 1024;
    const bf16* Wt = blockIdx.y ? Wt_kv : Wt_q;
    const float* gamma = blockIdx.y ? kv_g : q_g;
    const float* beta  = blockIdx.y ? kv_b : q_b;
    bf16* out = blockIdx.y ? ckv : cq;

    const int m0 = blockIdx.x * 16;
    const int wv = threadIdx.x >> 6;
    const int lane = threadIdx.x & 63;
    const int g = lane >> 4;
    const int ln16 = lane & 15;
    const int ncol0 = wv * 64;

    f32x4 acc[4] = {};
    const float* arow = x + (size_t)(m0 + ln16) * K + g * 8;
    for (int k0 = 0; k0 < K; k0 += 32) {
        f32x4 f0 = *(const f32x4*)(arow + k0);
        f32x4 f1 = *(const f32x4*)(arow + k0 + 4);
        bf16x8 a;
#pragma unroll
        for (int j = 0; j < 4; ++j) { a[j] = (bf16)f0[j]; a[4 + j] = (bf16)f1[j]; }
#pragma unroll
        for (int t = 0; t < 4; ++t) {
            const bf16* bp = Wt + (size_t)(ncol0 + 16 * t + ln16) * K + k0 + g * 8;
            bf16x8 b = *(const bf16x8*)bp;
            acc[t] = __builtin_amdgcn_mfma_f32_16x16x32_bf16(a, b, acc[t], 0, 0, 0);
        }
    }

    float s1[4], s2[4];
#pragma unroll
    for (int r = 0; r < 4; ++r) {
        float a = 0.f, b = 0.f;
#pragma unroll
        for (int t = 0; t < 4; ++t) { float v = acc[t][r]; a += v; b += v * v; }
        s1[r] = rowsum16(a); s2[r] = rowsum16(b);
    }
    __shared__ float red1[4][16];
    __shared__ float red2[4][16];
    if (ln16 == 0) {
#pragma unroll
        for (int r = 0; r < 4; ++r) {
            red1[wv][g * 4 + r] = s1[r];
            red2[wv][g * 4 + r] = s2[r];
        }
    }
    __syncthreads();
#pragma unroll
    for (int r = 0; r < 4; ++r) {
        int row = g * 4 + r;
        float t1 = red1[0][row] + red1[1][row] + red1[2][row] + red1[3][row];
        float t2 = red2[0][row] + red2[1][row] + red2[2][row] + red2[3][row];
        float mu = t1 * (1.0f / 256.0f);
        float var = t2 * (1.0f / 256.0f) - mu * mu;
        float rs = rsqrtf(var + 1e-5f);
#pragma unroll
        for (int t = 0; t < 4; ++t) {
            int col = ncol0 + 16 * t + ln16;
            float v = (acc[t][r] - mu) * rs * gamma[col] + beta[col];
            out[(size_t)(m0 + row) * PROJ + col] = (bf16)v;
        }
    }
}

// ---------------------------------------------------------------------------
// m97-style LDS-staged MFMA GEMM. BM=64, BN=128, BK=32, 4 waves/block,
// each wave computes 32x64. A[M][K] row-major bf16, Bt[N][K] n-major bf16.
// Staging: global_load_lds width=16 (3 insts/wave/K-step), 2-barrier K-loop.
// MODE 0: C[M][N] row-major, OutT.
// MODE 1: C = head-major bf16 [b*16+h][2048][64], values pre-scaled by QSCALE.
// MODE 2: cols<1024 -> C = Kh head-major; cols>=1024 -> C2 = Vt [bh][64][2048]
template <int MODE, typename OutT>
__global__ __launch_bounds__(256) void gemm_lds_kernel(
    const bf16* __restrict__ A, const bf16* __restrict__ Bt,
    OutT* __restrict__ C, bf16* __restrict__ C2, int M, int N, int K) {
    __shared__ alignas(16) bf16 tA[64 * 32];    // 4 KB, rows of 64B
    __shared__ alignas(16) bf16 tB[128 * 32];   // 8 KB

    const int w = threadIdx.x >> 6;
    const int lane = threadIdx.x & 63;
    const int g = lane >> 4;
    const int ln16 = lane & 15;
    const int wr = w >> 1;          // 0..1  (32-row slab)
    const int wc = w & 1;           // 0..1  (64-col slab)

    const int m0 = blockIdx.x * 64;
    const int n0 = blockIdx.y * 128;

    // staging source pointers (per-lane): chunk = 16B; row has 4 chunks
    const int crow = lane >> 2;     // 0..15
    const int ckc = lane & 3;       // chunk within row
    const bf16* gA  = A  + (size_t)(m0 + w * 16 + crow) * K + ckc * 8;
    const bf16* gB0 = Bt + (size_t)(n0 + w * 16 + crow) * K + ckc * 8;
    const bf16* gB1 = Bt + (size_t)(n0 + 64 + w * 16 + crow) * K + ckc * 8;
    // staging LDS dests (wave-uniform)
    char* lA  = (char*)tA + w * 1024;
    char* lB0 = (char*)tB + w * 1024;
    char* lB1 = (char*)tB + 4096 + w * 1024;

    f32x4 acc[2][4] = {};
    for (int k0 = 0; k0 < K; k0 += 32) {
        gl2lds16(gA + k0, lA);
        gl2lds16(gB0 + k0, lB0);
        gl2lds16(gB1 + k0, lB1);
        __syncthreads();            // drains vmcnt: tiles staged

        bf16x8 af[2], bf[4];
#pragma unroll
        for (int s = 0; s < 2; ++s)
            af[s] = *(const bf16x8*)(tA + (wr * 32 + s * 16 + ln16) * 32 + g * 8);
#pragma unroll
        for (int t = 0; t < 4; ++t)
            bf[t] = *(const bf16x8*)(tB + (wc * 64 + t * 16 + ln16) * 32 + g * 8);
#pragma unroll
        for (int s = 0; s < 2; ++s)
#pragma unroll
            for (int t = 0; t < 4; ++t)
                acc[s][t] = __builtin_amdgcn_mfma_f32_16x16x32_bf16(
                    af[s], bf[t], acc[s][t], 0, 0, 0);
        __syncthreads();            // reads done before next overwrite
    }

#pragma unroll
    for (int s = 0; s < 2; ++s)
#pragma unroll
        for (int t = 0; t < 4; ++t) {
            const int col = n0 + wc * 64 + t * 16 + ln16;
            const int tok0 = m0 + wr * 32 + s * 16 + g * 4;
            if (MODE == 2 && col >= 1024) {
                int cc = col - 1024;
                int h = cc >> 6, d = cc & 63;
                int b = tok0 >> 11, sq = tok0 & 2047;
                bf16x4 pk;
#pragma unroll
                for (int r = 0; r < 4; ++r) pk[r] = (bf16)acc[s][t][r];
                *(bf16x4*)(C2 + ((size_t)((b * 16 + h) * 64 + d) * SEQ + sq)) = pk;
            } else {
#pragma unroll
                for (int r = 0; r < 4; ++r) {
                    int row = tok0 + r;
                    float v = acc[s][t][r];
                    if (MODE == 0) {
                        C[(size_t)row * N + col] = (OutT)v;
                    } else {
                        if (MODE == 1) v *= QSCALE;
                        int h = col >> 6, d = col & 63;
                        int b = row >> 11, sq = row & 2047;
                        C[((size_t)((b * 16 + h) * 2048 + sq)) * 64 + d] = (OutT)v;
                    }
                }
            }
        }
}

// ---------------------------------------------------------------------------
// Split-K paired flash attention (fixed-max softmax => k-split is a pure sum).
__device__ __forceinline__ void load_kfrags(const bf16* __restrict__ Kbh, int k0,
                                            int g, int ln16, bf16x8* Kf) {
#pragma unroll
    for (int c = 0; c < 4; ++c) {
        const bf16* kp = Kbh + (size_t)(k0 + 16 * c + ln16) * DH + g * 8;
        Kf[2 * c]     = *(const bf16x8*)kp;
        Kf[2 * c + 1] = *(const bf16x8*)(kp + 32);
    }
}
__device__ __forceinline__ void load_vfrags(const bf16* __restrict__ Vbh, int k0,
                                            int g, int ln16, bf16x8* Vf) {
#pragma unroll
    for (int t = 0; t < 4; ++t) {
        const bf16* vp = Vbh + (size_t)(16 * t + ln16) * SEQ + k0 + g * 8;
        Vf[2 * t]     = *(const bf16x8*)vp;
        Vf[2 * t + 1] = *(const bf16x8*)(vp + 32);
    }
}

__device__ __forceinline__ void qk_exp(
    int k0, int qb, bool masked, int g, int ln16,
    bf16x8 aq0, bf16x8 aq1, const bf16x8* Kf,
    unsigned short* __restrict__ pb, float* liacc) {
    f32x4 sc[4];
#pragma unroll
    for (int c = 0; c < 4; ++c) {
        f32x4 z = {};
        z = __builtin_amdgcn_mfma_f32_16x16x32_bf16(aq0, Kf[2 * c], z, 0, 0, 0);
        z = __builtin_amdgcn_mfma_f32_16x16x32_bf16(aq1, Kf[2 * c + 1], z, 0, 0, 0);
        sc[c] = z;
    }
    if (masked) {
#pragma unroll
        for (int r = 0; r < 4; ++r) {
            int qrow = qb + g * 4 + r;
#pragma unroll
            for (int c = 0; c < 4; ++c) {
                int col = k0 + 16 * c + ln16;
                if (col > qrow) sc[c][r] = NEG_BIG;
            }
        }
    }
#pragma unroll
    for (int r = 0; r < 4; ++r) {
        float p0 = EXP2(sc[0][r]), p1 = EXP2(sc[1][r]);
        float p2 = EXP2(sc[2][r]), p3 = EXP2(sc[3][r]);
        sc[0][r] = p0; sc[1][r] = p1; sc[2][r] = p2; sc[3][r] = p3;
        liacc[r] += (p0 + p1) + (p2 + p3);
    }
#pragma unroll
    for (int c = 0; c < 4; ++c)
#pragma unroll
        for (int r = 0; r < 4; ++r) {
            bf16 pv = (bf16)sc[c][r];
            pb[(g * 4 + r) * PSTR + 16 * c + ln16] =
                __builtin_bit_cast(unsigned short, pv);
        }
}

__device__ __forceinline__ void pv_accum(
    const unsigned short* __restrict__ pb, int g, int ln16,
    const bf16x8* Vf, f32x4* o) {
    bf16x8 pf0 = *(const bf16x8*)(pb + ln16 * PSTR + g * 8);
    bf16x8 pf1 = *(const bf16x8*)(pb + ln16 * PSTR + 32 + g * 8);
#pragma unroll
    for (int t = 0; t < 4; ++t) {
        o[t] = __builtin_amdgcn_mfma_f32_16x16x32_bf16(pf0, Vf[2 * t], o[t], 0, 0, 0);
        o[t] = __builtin_amdgcn_mfma_f32_16x16x32_bf16(pf1, Vf[2 * t + 1], o[t], 0, 0, 0);
    }
}

// __launch_bounds__(256,2): (256,4) clamps to 64 VGPR and spills (round 7).
__global__ __launch_bounds__(256, 2) void attn_kernel(
    const bf16* __restrict__ Qh, const bf16* __restrict__ Kh,
    const bf16* __restrict__ Vt,
    float* __restrict__ Opart, float* __restrict__ lpart) {
    __shared__ alignas(16) unsigned short pbuf[4][2][16 * PSTR];

    const int wv = threadIdx.x >> 6;
    const int lane = threadIdx.x & 63;
    const int g = lane >> 4;
    const int ln16 = lane & 15;

    const int wid = blockIdx.x * 4 + wv;   // 0..4095
    const int pid = wid >> 1;              // 0..2047
    const int sp  = wid & 1;               // kt parity
    const int bh = pid & 31;
    const int p  = pid >> 5;               // 0..63
    const int qbL = p * 16;
    const int qbH = (127 - p) * 16;
    const int lastL = p >> 2;
    const int lastH = (127 - p) >> 2;

    const bf16* Kbh = Kh + (size_t)bh * SEQ * DH;
    const bf16* Vbh = Vt + (size_t)bh * DH * SEQ;

    const bf16* qpL = Qh + ((size_t)bh * SEQ + qbL + ln16) * DH + g * 8;
    const bf16* qpH = Qh + ((size_t)bh * SEQ + qbH + ln16) * DH + g * 8;
    bf16x8 aqL0 = *(const bf16x8*)qpL, aqL1 = *(const bf16x8*)(qpL + 32);
    bf16x8 aqH0 = *(const bf16x8*)qpH, aqH1 = *(const bf16x8*)(qpH + 32);

    f32x4 oL[4] = {}, oH[4] = {};
    float liL[4] = {}, liH[4] = {};

    unsigned short* pbL = &pbuf[wv][0][0];
    unsigned short* pbH = &pbuf[wv][1][0];

    bf16x8 Kf[8], Kn[8], Vf[8];
    load_kfrags(Kbh, sp * 64, g, ln16, Kf);
#pragma unroll
    for (int i = 0; i < 8; ++i) Kn[i] = Kf[i];

    for (int kt = sp; kt <= lastH; kt += 2) {
        const int k0 = kt * 64;
        load_vfrags(Vbh, k0, g, ln16, Vf);
        if (kt + 2 <= lastH) load_kfrags(Kbh, k0 + 128, g, ln16, Kn);

        const bool actL = (kt <= lastL);
        if (actL) qk_exp(k0, qbL, kt == lastL, g, ln16, aqL0, aqL1, Kf, pbL, liL);
        qk_exp(k0, qbH, kt == lastH, g, ln16, aqH0, aqH1, Kf, pbH, liH);
        __asm__ volatile("s_waitcnt lgkmcnt(0)" ::: "memory");
        if (actL) pv_accum(pbL, g, ln16, Vf, oL);
        pv_accum(pbH, g, ln16, Vf, oH);

#pragma unroll
        for (int i = 0; i < 8; ++i) Kf[i] = Kn[i];
    }

    const int slotL = (pid * 2 + sp) * 2;
    const int slotH = slotL + 1;
    float* OL = Opart + (size_t)slotL * 1024;
    float* OH = Opart + (size_t)slotH * 1024;
#pragma unroll
    for (int t = 0; t < 4; ++t)
#pragma unroll
        for (int r = 0; r < 4; ++r) {
            int e = (g * 4 + r) * 64 + 16 * t + ln16;
            OL[e] = oL[t][r];
            OH[e] = oH[t][r];
        }
#pragma unroll
    for (int r = 0; r < 4; ++r) {
        float sL = rowsum16(liL[r]);
        float sH = rowsum16(liH[r]);
        if (ln16 == 0) {
            lpart[slotL * 16 + g * 4 + r] = sL;
            lpart[slotH * 16 + g * 4 + r] = sH;
        }
    }
}

// ---------------------------------------------------------------------------
// Combine: sum the two parity partials, normalize, write AT token-major.
__global__ __launch_bounds__(256) void combine_kernel(
    const float* __restrict__ Opart, const float* __restrict__ lpart,
    bf16* __restrict__ AT) {
    int idx = blockIdx.x * 256 + threadIdx.x;      // 32*2048*64 = 4.19M
    int d = idx & 63;
    int s = (idx >> 6) & 2047;
    int bh = idx >> 17;
    int qt = s >> 4, row = s & 15;
    int which = (qt >= 64) ? 1 : 0;
    int p = which ? (127 - qt) : qt;
    int pid = p * 32 + bh;
    int s0 = (pid * 2 + 0) * 2 + which;
    int s1 = (pid * 2 + 1) * 2 + which;
    float O = Opart[(size_t)s0 * 1024 + row * 64 + d] +
              Opart[(size_t)s1 * 1024 + row * 64 + d];
    float l = lpart[s0 * 16 + row] + lpart[s1 * 16 + row];
    int token = (bh >> 4) * 2048 + s;
    int col = (bh & 15) * 64 + d;
    AT[(size_t)token * 1024 + col] = (bf16)(O / l);
}

// ---------------------------------------------------------------------------
extern "C" void kernel_launch(void* const* d_in, const int* in_sizes, int n_in,
                              void* d_out, int out_size, void* d_ws, size_t ws_size,
                              hipStream_t stream) {
    const float* x     = (const float*)d_in[0];
    const float* W_dq  = (const float*)d_in[1];
    const float* W_uq  = (const float*)d_in[2];
    const float* q_g   = (const float*)d_in[3];
    const float* q_b   = (const float*)d_in[4];
    const float* W_dkv = (const float*)d_in[5];
    const float* W_ukv = (const float*)d_in[6];
    const float* kv_g  = (const float*)d_in[7];
    const float* kv_b  = (const float*)d_in[8];
    const float* W_o   = (const float*)d_in[9];

    char* ws = (char*)d_ws;
    size_t off = 0;
    bf16* Wo16   = (bf16*)(ws + off); off += (size_t)D_MODEL * D_MODEL * 2;
    bf16* Wt_dq  = (bf16*)(ws + off); off += (size_t)PROJ * D_MODEL * 2;
    bf16* Wt_dkv = (bf16*)(ws + off); off += (size_t)PROJ * D_MODEL * 2;
    bf16* Wt_uq  = (bf16*)(ws + off); off += (size_t)D_MODEL * PROJ * 2;
    bf16* Wt_ukv = (bf16*)(ws + off); off += (size_t)(2 * D_MODEL) * PROJ * 2;
    bf16* cq     = (bf16*)(ws + off); off += (size_t)TOK * PROJ * 2;
    bf16* ckv    = (bf16*)(ws + off); off += (size_t)TOK * PROJ * 2;
    bf16* Qh     = (bf16*)(ws + off); off += (size_t)TOK * D_MODEL * 2;
    bf16* Kh     = (bf16*)(ws + off); off += (size_t)TOK * D_MODEL * 2;
    bf16* Vt     = (bf16*)(ws + off); off += (size_t)TOK * D_MODEL * 2;
    bf16* AT     = (bf16*)(ws + off); off += (size_t)TOK * D_MODEL * 2;
    float* Opart = (float*)(ws + off); off += (size_t)8192 * 1024 * 4;   // 33.5 MB
    float* lpart = (float*)(ws + off); off += (size_t)8192 * 16 * 4;

    prep_weights_kernel<<<2048, 256, 0, stream>>>(
        W_o, W_dq, W_dkv, W_uq, W_ukv, Wo16, Wt_dq, Wt_dkv, Wt_uq, Wt_ukv);

    gemm_ln_kernel<<<dim3(TOK / 16, 2), 256, 0, stream>>>(
        x, Wt_dq, Wt_dkv, q_g, q_b, kv_g, kv_b, cq, ckv);

    // Q = cq @ W_uq -> head-major Qh (QSCALE folded)
    gemm_lds_kernel<1, bf16><<<dim3(TOK / 64, D_MODEL / 128), 256, 0, stream>>>(
        cq, Wt_uq, Qh, nullptr, TOK, D_MODEL, PROJ);
    // KV = ckv @ W_ukv -> Kh + transposed Vt
    gemm_lds_kernel<2, bf16><<<dim3(TOK / 64, (2 * D_MODEL) / 128), 256, 0, stream>>>(
        ckv, Wt_ukv, Kh, Vt, TOK, 2 * D_MODEL, PROJ);

    attn_kernel<<<1024, 256, 0, stream>>>(Qh, Kh, Vt, Opart, lpart);
    combine_kernel<<<(32 * 2048 * 64) / 256, 256, 0, stream>>>(Opart, lpart, AT);

    // out = attn @ W_o^T (fp32 out)
    gemm_lds_kernel<0, float><<<dim3(TOK / 64, D_MODEL / 128), 256, 0, stream>>>(
        AT, Wo16, (float*)d_out, nullptr, TOK, D_MODEL, D_MODEL);
}